// Round 1
// baseline (17030.173 us; speedup 1.0000x reference)
//
#include <hip/hip_runtime.h>
#include <hip/hip_bf16.h>
#include <math.h>

// Problem dims
#define B_  128
#define T_  512
#define I_  256
#define H_  512
#define O_  256
#define NP  2048            // 4*H (gate-interleaved n' = h*4+g)
#define BT  65536           // B*T
#define HB  65536           // H*B

// ---------------------------------------------------------------------------
// Prep: build transposed/gathered weight layouts + fused bias vectors.
//  Wt  [K=512][NP]   : Wt[k][h*4+g]   = Wh_g[h][k]      (recurrent, transposed+interleaved)
//  Wg  [NP][I]       : Wg[h*4+g][i]   = Wx_g[h][i]      (x-weights, gathered rows for GEMM A)
//  WgT [I][NP]       : WgT[i][h*4+g]  = Wx_g[h][i]      (for fallback in-step x projection)
//  WphT[H][O]        : WphT[h][o]     = Wph[o][h]
//  xb  [NP]          : Wx_b_g[h] + b_g[h]
//  hb  [NP]          : Wh_b_g[h]
//  pb  [O]           : Wph_b[o] + bp[o]
// ---------------------------------------------------------------------------
struct PrepArgs {
    const float* Whw[4];
    const float* Wxw[4];
    const float* Wxb[4];
    const float* Whb[4];
    const float* bg[4];
    const float* Wph_w;
    const float* Wph_b;
    const float* bp;
    float* Wt; float* Wg; float* WgT; float* WphT;
    float* xb; float* hb; float* pb;
};

#define PREP_TOTAL (1048576 + 524288 + 524288 + 131072 + 2048 + 2048 + 256)

__global__ __launch_bounds__(256) void k_prep(PrepArgs a) {
    int idx = blockIdx.x * 256 + threadIdx.x;
    if (idx >= PREP_TOTAL) return;
    int q = idx;
    if (q < 1048576) {                       // Wt [512][2048]
        int k = q >> 11, n = q & 2047;
        int g = n & 3, h = n >> 2;
        a.Wt[q] = a.Whw[g][h * H_ + k];
        return;
    }
    q -= 1048576;
    if (q < 524288) {                        // Wg [2048][256]
        int n = q >> 8, i = q & 255;
        int g = n & 3, h = n >> 2;
        a.Wg[q] = a.Wxw[g][h * I_ + i];
        return;
    }
    q -= 524288;
    if (q < 524288) {                        // WgT [256][2048]
        int i = q >> 11, n = q & 2047;
        int g = n & 3, h = n >> 2;
        a.WgT[q] = a.Wxw[g][h * I_ + i];
        return;
    }
    q -= 524288;
    if (q < 131072) {                        // WphT [512][256]
        int h = q >> 8, o = q & 255;
        a.WphT[q] = a.Wph_w[o * H_ + h];
        return;
    }
    q -= 131072;
    if (q < 2048) {                          // xb
        int g = q & 3, h = q >> 2;
        a.xb[q] = a.Wxb[g][h] + a.bg[g][h];
        return;
    }
    q -= 2048;
    if (q < 2048) {                          // hb
        int g = q & 3, h = q >> 2;
        a.hb[q] = a.Whb[g][h];
        return;
    }
    q -= 2048;
    a.pb[q] = a.Wph_b[q] + a.bp[q];          // pb
}

// ---------------------------------------------------------------------------
// Transpose x: xT2[i][t*128+b] = x[b][t][i]
// 32x32 LDS tile transpose, grid (BT/32, I/32), 256 threads (32x8).
// ---------------------------------------------------------------------------
__global__ __launch_bounds__(256) void k_transpose(const float* __restrict__ x,
                                                   float* __restrict__ xT2) {
    __shared__ float lds[32][33];
    int tid = threadIdx.x;
    int tx = tid & 31, ty = tid >> 5;       // 32 x 8
    int j0 = blockIdx.x * 32;               // j = t*128 + b; tile within one t (32|128)
    int i0 = blockIdx.y * 32;
    int t  = j0 >> 7;
    int b0 = j0 & 127;
#pragma unroll
    for (int rr = 0; rr < 4; ++rr) {
        int jj = ty + rr * 8;               // b offset
        lds[jj][tx] = x[((size_t)(b0 + jj) * T_ + t) * I_ + i0 + tx];
    }
    __syncthreads();
#pragma unroll
    for (int rr = 0; rr < 4; ++rr) {
        int ii = ty + rr * 8;
        xT2[(size_t)(i0 + ii) * BT + j0 + tx] = lds[tx][ii];
    }
}

// ---------------------------------------------------------------------------
// Big input-projection GEMM: xp[m][j] = sum_i Wg[m][i]*xT2[i][j] + xb[m]
// M=2048 (n'), N=65536 (j=t*128+b), K=256. Tile 128x128, Ktile 16, micro 8x8.
// ---------------------------------------------------------------------------
__global__ __launch_bounds__(256, 1) void k_xgemm(const float* __restrict__ A,   // Wg [2048][256]
                                                  const float* __restrict__ Bm,  // xT2 [256][65536]
                                                  const float* __restrict__ bias,// xb
                                                  float* __restrict__ C) {       // xp [2048][65536]
    __shared__ float As[16][128];
    __shared__ float Bs[16][128];
    int tid = threadIdx.x;
    int tx = tid & 15, ty = tid >> 4;
    int m0 = blockIdx.y * 128, j0 = blockIdx.x * 128;
    float acc[8][8];
#pragma unroll
    for (int i = 0; i < 8; ++i)
#pragma unroll
        for (int j = 0; j < 8; ++j) acc[i][j] = 0.f;

    for (int kt = 0; kt < I_; kt += 16) {
#pragma unroll
        for (int pp = 0; pp < 2; ++pp) {     // stage A (transposed into k-major)
            int p = tid + pp * 256;
            int row = p >> 2, kq = (p & 3) << 2;
            float4 av = *(const float4*)&A[(size_t)(m0 + row) * I_ + kt + kq];
            As[kq + 0][row] = av.x; As[kq + 1][row] = av.y;
            As[kq + 2][row] = av.z; As[kq + 3][row] = av.w;
        }
#pragma unroll
        for (int pp = 0; pp < 2; ++pp) {     // stage B (already k-major)
            int p = tid + pp * 256;
            int krow = p >> 5, c4 = (p & 31) << 2;
            *(float4*)&Bs[krow][c4] =
                *(const float4*)&Bm[(size_t)(kt + krow) * BT + j0 + c4];
        }
        __syncthreads();
#pragma unroll
        for (int k = 0; k < 16; ++k) {
            float a[8], b[8];
            *(float4*)&a[0] = *(const float4*)&As[k][ty * 4];
            *(float4*)&a[4] = *(const float4*)&As[k][64 + ty * 4];
            *(float4*)&b[0] = *(const float4*)&Bs[k][tx * 4];
            *(float4*)&b[4] = *(const float4*)&Bs[k][64 + tx * 4];
#pragma unroll
            for (int i = 0; i < 8; ++i)
#pragma unroll
                for (int j = 0; j < 8; ++j) acc[i][j] += a[i] * b[j];
        }
        __syncthreads();
    }
#pragma unroll
    for (int i = 0; i < 8; ++i) {
        int mrow = (i < 4) ? (ty * 4 + i) : (64 + ty * 4 + (i - 4));
        int m = m0 + mrow;
        float bv = bias[m];
        float4 v0 = {acc[i][0] + bv, acc[i][1] + bv, acc[i][2] + bv, acc[i][3] + bv};
        float4 v1 = {acc[i][4] + bv, acc[i][5] + bv, acc[i][6] + bv, acc[i][7] + bv};
        *(float4*)&C[(size_t)m * BT + j0 + tx * 4] = v0;
        *(float4*)&C[(size_t)m * BT + j0 + 64 + tx * 4] = v1;
    }
}

// ---------------------------------------------------------------------------
// Per-timestep recurrent kernel.
// Grid 256 = 128 n'-tiles (16 wide) x 2 b-halves. Block 256 = 4 waves (K split).
// lane = batch element; 16 gate-interleaved n' columns in registers;
// weights wave-uniform (scalar-operand FMA). LDS reduce + in-block epilogue.
// ---------------------------------------------------------------------------
__device__ inline float sigm(float v) { return 1.f / (1.f + expf(-v)); }

template <bool USE_XP>
__global__ __launch_bounds__(256, 1) void k_step(const float* __restrict__ Wt,   // [512][2048]
                                                 const float* __restrict__ WgT,  // [256][2048]
                                                 const float* __restrict__ xp,   // [2048][BT]
                                                 const float* __restrict__ xT2,  // [256][BT]
                                                 const float* __restrict__ xb,   // [2048]
                                                 const float* __restrict__ hb,   // [2048]
                                                 float* __restrict__ hist,       // [513][512][128]
                                                 float* __restrict__ cT,         // [512][128]
                                                 int t) {
    __shared__ float red[4][16][64];
    int tid = threadIdx.x;
    int wave = tid >> 6, lane = tid & 63;
    int nt = blockIdx.x >> 1, bh = blockIdx.x & 1;
    int n0 = nt * 16, b0 = bh * 64;
    int b = b0 + lane;

    const float* hrow = hist + (size_t)t * HB;
    float acc[16];
#pragma unroll
    for (int j = 0; j < 16; ++j) acc[j] = 0.f;

    {   // recurrent part: K chunk of 128 per wave
        int k0 = wave * 128;
        const float* hp = hrow + (size_t)k0 * B_ + b;
        const float* wp = Wt + (size_t)k0 * NP + n0;
        float hv[8];
#pragma unroll
        for (int u = 0; u < 8; ++u) hv[u] = hp[u * B_];
        for (int kb = 0; kb < 128; kb += 8) {
            float hn[8];
            if (kb + 8 < 128) {
                const float* hp2 = hp + (size_t)(kb + 8) * B_;
#pragma unroll
                for (int u = 0; u < 8; ++u) hn[u] = hp2[u * B_];
            }
#pragma unroll
            for (int u = 0; u < 8; ++u) {
                const float* w = wp + (size_t)(kb + u) * NP;
                float h0 = hv[u];
#pragma unroll
                for (int j = 0; j < 4; ++j) {
                    float4 wv = *(const float4*)(w + j * 4);
                    acc[j * 4 + 0] += h0 * wv.x;
                    acc[j * 4 + 1] += h0 * wv.y;
                    acc[j * 4 + 2] += h0 * wv.z;
                    acc[j * 4 + 3] += h0 * wv.w;
                }
            }
#pragma unroll
            for (int u = 0; u < 8; ++u) hv[u] = hn[u];
        }
    }
    if (!USE_XP) {   // fallback: fold x-projection in (I chunk of 64 per wave)
        int i0 = wave * 64;
        const float* xpp = xT2 + (size_t)i0 * BT + (size_t)t * B_ + b;
        const float* wp  = WgT + (size_t)i0 * NP + n0;
#pragma unroll 4
        for (int ii = 0; ii < 64; ++ii) {
            float xv = xpp[(size_t)ii * BT];
            const float* w = wp + (size_t)ii * NP;
#pragma unroll
            for (int j = 0; j < 4; ++j) {
                float4 wv = *(const float4*)(w + j * 4);
                acc[j * 4 + 0] += xv * wv.x;
                acc[j * 4 + 1] += xv * wv.y;
                acc[j * 4 + 2] += xv * wv.z;
                acc[j * 4 + 3] += xv * wv.w;
            }
        }
    }
#pragma unroll
    for (int j = 0; j < 16; ++j) red[wave][j][lane] = acc[j];
    __syncthreads();

    // epilogue: thread -> (b_l, h_i), owns all 4 gates of (b, h)
    int b_l = tid & 63, h_i = tid >> 6;
    int n = n0 + h_i * 4;
    int h = nt * 4 + h_i;
    int bb = b0 + b_l;
    float pre[4];
#pragma unroll
    for (int g = 0; g < 4; ++g) {
        int j = h_i * 4 + g;
        pre[g] = red[0][j][b_l] + red[1][j][b_l] + red[2][j][b_l] + red[3][j][b_l];
        pre[g] += hb[n + g];
        if (USE_XP)
            pre[g] += xp[(size_t)(n + g) * BT + (size_t)t * B_ + bb];
        else
            pre[g] += xb[n + g];
    }
    float iv = sigm(pre[0]);
    float fv = sigm(pre[1]);
    float gv = tanhf(pre[2]);
    float ov = sigm(pre[3]);
    float c  = cT[h * B_ + bb];
    float cn = gv * iv + c * fv;
    cT[h * B_ + bb] = cn;
    hist[(size_t)(t + 1) * HB + h * B_ + bb] = tanhf(cn) * ov;
}

// ---------------------------------------------------------------------------
// Output projection: pT[t][o][b] = sum_h hist[t+1][h][b]*WphT[h][o] + pb[o]
// Grid (32, 512): 16 o-tiles x 2 b-halves, per t. Block 256 = 4 waves (K split).
// ---------------------------------------------------------------------------
__global__ __launch_bounds__(256, 1) void k_outproj(const float* __restrict__ WphT, // [512][256]
                                                    const float* __restrict__ pb,   // [256]
                                                    const float* __restrict__ hist,
                                                    float* __restrict__ pT) {       // [512][256][128]
    __shared__ float red[4][16][64];
    int tid = threadIdx.x;
    int wave = tid >> 6, lane = tid & 63;
    int t = blockIdx.y;
    int ot = blockIdx.x >> 1, bh = blockIdx.x & 1;
    int o0 = ot * 16, b0 = bh * 64;
    int b = b0 + lane;

    const float* hrow = hist + (size_t)(t + 1) * HB;
    float acc[16];
#pragma unroll
    for (int j = 0; j < 16; ++j) acc[j] = 0.f;

    int k0 = wave * 128;
    const float* hp = hrow + (size_t)k0 * B_ + b;
    const float* wp = WphT + (size_t)k0 * O_ + o0;
    float hv[8];
#pragma unroll
    for (int u = 0; u < 8; ++u) hv[u] = hp[u * B_];
    for (int kb = 0; kb < 128; kb += 8) {
        float hn[8];
        if (kb + 8 < 128) {
            const float* hp2 = hp + (size_t)(kb + 8) * B_;
#pragma unroll
            for (int u = 0; u < 8; ++u) hn[u] = hp2[u * B_];
        }
#pragma unroll
        for (int u = 0; u < 8; ++u) {
            const float* w = wp + (size_t)(kb + u) * O_;
            float h0 = hv[u];
#pragma unroll
            for (int j = 0; j < 4; ++j) {
                float4 wv = *(const float4*)(w + j * 4);
                acc[j * 4 + 0] += h0 * wv.x;
                acc[j * 4 + 1] += h0 * wv.y;
                acc[j * 4 + 2] += h0 * wv.z;
                acc[j * 4 + 3] += h0 * wv.w;
            }
        }
#pragma unroll
        for (int u = 0; u < 8; ++u) hv[u] = hn[u];
    }
#pragma unroll
    for (int j = 0; j < 16; ++j) red[wave][j][lane] = acc[j];
    __syncthreads();

    int b_l = tid & 63, oi = tid >> 6;
    int bb = b0 + b_l;
#pragma unroll
    for (int g = 0; g < 4; ++g) {
        int j = oi * 4 + g;
        int o = o0 + j;
        float v = red[0][j][b_l] + red[1][j][b_l] + red[2][j][b_l] + red[3][j][b_l] + pb[o];
        pT[(size_t)t * (O_ * B_) + (size_t)o * B_ + bb] = v;
    }
}

// ---------------------------------------------------------------------------
// Softmax over O + layout change to d_out[b][t][o].
// Grid 2048 = 512 t x 4 b-quarters(32). Block 256 (= 32 b x 8 o-chunks).
// ---------------------------------------------------------------------------
__global__ __launch_bounds__(256, 1) void k_softmax(const float* __restrict__ pT,
                                                    float* __restrict__ out) {
    __shared__ float sm[32][257];
    __shared__ float rmax[32][8];
    __shared__ float rsum[32][8];
    int tid = threadIdx.x;
    int t = blockIdx.x >> 2, bq = blockIdx.x & 3;
    int b0 = bq * 32;
    const float* src = pT + (size_t)t * (O_ * B_);

#pragma unroll 4
    for (int it = 0; it < 32; ++it) {
        int idx = it * 256 + tid;           // 8192 = 256 o x 32 b
        int o = idx >> 5, b_l = idx & 31;
        sm[b_l][o] = src[(size_t)o * B_ + b0 + b_l];
    }
    __syncthreads();

    int b_l = tid >> 3, oc = tid & 7;       // 32 b x 8 chunks of 32 o
    float m = -3.4e38f;
#pragma unroll 4
    for (int oo = 0; oo < 32; ++oo) m = fmaxf(m, sm[b_l][oc * 32 + oo]);
    rmax[b_l][oc] = m;
    __syncthreads();
    float mm = rmax[b_l][0];
#pragma unroll
    for (int c = 1; c < 8; ++c) mm = fmaxf(mm, rmax[b_l][c]);

    float s = 0.f;
#pragma unroll 4
    for (int oo = 0; oo < 32; ++oo) s += expf(sm[b_l][oc * 32 + oo] - mm);
    rsum[b_l][oc] = s;
    __syncthreads();
    float st = 0.f;
#pragma unroll
    for (int c = 0; c < 8; ++c) st += rsum[b_l][c];
    float inv = 1.f / st;

    int bb = b0 + b_l;
    float* dst = out + ((size_t)bb * T_ + t) * O_ + oc * 32;
#pragma unroll 4
    for (int oo = 0; oo < 32; ++oo)
        dst[oo] = expf(sm[b_l][oc * 32 + oo] - mm) * inv;
}

// ---------------------------------------------------------------------------
extern "C" void kernel_launch(void* const* d_in, const int* in_sizes, int n_in,
                              void* d_out, int out_size, void* d_ws, size_t ws_size,
                              hipStream_t stream) {
    const float* x = (const float*)d_in[0];

    float* ws = (float*)d_ws;
    size_t off = 0;
    auto alloc = [&](size_t n) { float* p = ws + off; off += n; return p; };

    float* hist = alloc((size_t)513 * HB);      // h history (slot 0 = h_{-1} = 0)
    float* cT   = alloc(HB);                    // cell state, transposed [h][b]
    float* Wt   = alloc((size_t)512 * NP);
    float* Wg   = alloc((size_t)NP * I_);
    float* WgT  = alloc((size_t)I_ * NP);
    float* WphT = alloc((size_t)H_ * O_);
    float* xb   = alloc(NP);
    float* hb   = alloc(NP);
    float* pb   = alloc(O_);
    float* xT2  = alloc((size_t)I_ * BT);       // reused as pT after the scan
    size_t baseBytes = off * sizeof(float);
    size_t xpBytes   = (size_t)NP * BT * sizeof(float);

    bool useXp = (ws_size >= baseBytes + xpBytes);
    float* xp = ws + off;                       // only valid if useXp
    float* pT = xT2;

    if (ws_size < baseBytes) return;            // cannot run — fail cleanly

    // zero h_{-1} and c
    hipMemsetAsync(hist, 0, HB * sizeof(float), stream);
    hipMemsetAsync(cT, 0, HB * sizeof(float), stream);

    PrepArgs pa;
    for (int g = 0; g < 4; ++g) {
        pa.Wxw[g] = (const float*)d_in[1 + 5 * g];
        pa.Wxb[g] = (const float*)d_in[2 + 5 * g];
        pa.Whw[g] = (const float*)d_in[3 + 5 * g];
        pa.Whb[g] = (const float*)d_in[4 + 5 * g];
        pa.bg[g]  = (const float*)d_in[5 + 5 * g];
    }
    pa.Wph_w = (const float*)d_in[21];
    pa.Wph_b = (const float*)d_in[22];
    pa.bp    = (const float*)d_in[23];
    pa.Wt = Wt; pa.Wg = Wg; pa.WgT = WgT; pa.WphT = WphT;
    pa.xb = xb; pa.hb = hb; pa.pb = pb;

    k_prep<<<(PREP_TOTAL + 255) / 256, 256, 0, stream>>>(pa);
    k_transpose<<<dim3(BT / 32, I_ / 32), 256, 0, stream>>>(x, xT2);

    if (useXp)
        k_xgemm<<<dim3(BT / 128, NP / 128), 256, 0, stream>>>(Wg, xT2, xb, xp);

    for (int t = 0; t < T_; ++t) {
        if (useXp)
            k_step<true><<<256, 256, 0, stream>>>(Wt, WgT, xp, xT2, xb, hb, hist, cT, t);
        else
            k_step<false><<<256, 256, 0, stream>>>(Wt, WgT, xp, xT2, xb, hb, hist, cT, t);
    }

    k_outproj<<<dim3(32, T_), 256, 0, stream>>>(WphT, pb, hist, pT);
    k_softmax<<<T_ * 4, 256, 0, stream>>>(pT, (float*)d_out);
}